// Round 17
// baseline (164.713 us; speedup 1.0000x reference)
//
#include <hip/hip_runtime.h>

// ResidualGNNLayer: h = x@W; gcn_norm gather-aggregate (CSR built per-call);
// +bias; LayerNorm; 0.5*h+0.5*x; relu.  N=100000, E=300000, D=256.
//
// Consolidated best-of: R6 gemm (66us measured) + R16 CSR/agg chain (~80us).
//
// ws layout:
//   h     : N*256 bf16                   51.2 MB
//   dv    : N floats  (deg -> dinv)       0.4 MB
//   cnt   : N ints                        0.4 MB
//   off   : N ints                        0.4 MB
//   cur   : N ints                        0.4 MB
//   bsum  : 512 ints
//   elist : E int2    {src, coef}         2.4 MB
//   Wf    : 65536 shorts (fragment-major) 128 KB

#define NN 100000
#define NE 300000
#define DD 256
#define NB 391    // ceil(NN/256)
#define GMB 1563  // ceil(NN/64)

typedef __attribute__((ext_vector_type(8))) short short8;
typedef __attribute__((ext_vector_type(4))) float f32x4;
typedef __attribute__((ext_vector_type(4))) unsigned short u16x4;

static __device__ __forceinline__ short f2bf(float f) {
  union { float f; unsigned u; } a; a.f = f;
  unsigned r = a.u + 0x7fffu + ((a.u >> 16) & 1u);
  return (short)(r >> 16);
}

static __device__ __forceinline__ float bf2f(short s) {
  return __uint_as_float((unsigned)(unsigned short)s << 16);
}

// packed f32x2 -> bf16x2 (RNE), single VOP3 instruction
static __device__ __forceinline__ unsigned cvtpk(float a, float b) {
  unsigned r;
  asm("v_cvt_pk_bf16_f32 %0, %1, %2" : "=v"(r) : "v"(a), "v"(b));
  return r;
}

__global__ __launch_bounds__(256) void k_hist(const int* __restrict__ ei,
                                              const float* __restrict__ ew,
                                              float* __restrict__ dv,
                                              int* __restrict__ cnt) {
  int e = blockIdx.x * 256 + threadIdx.x;
  if (e < NE) {
    int d = ei[NE + e];
    atomicAdd(&dv[d], ew[e]);
    atomicAdd(&cnt[d], 1);
  }
}

__global__ __launch_bounds__(256) void k_scan1(const int* __restrict__ cnt,
                                               int* __restrict__ off,
                                               int* __restrict__ bsum) {
  __shared__ int tmp[256];
  int t = threadIdx.x;
  int i = blockIdx.x * 256 + t;
  int v = (i < NN) ? cnt[i] : 0;
  tmp[t] = v;
  __syncthreads();
  for (int o = 1; o < 256; o <<= 1) {
    int u = (t >= o) ? tmp[t - o] : 0;
    __syncthreads();
    tmp[t] += u;
    __syncthreads();
  }
  if (i < NN) off[i] = tmp[t] - v;
  if (t == 255) bsum[blockIdx.x] = tmp[t];
}

__global__ __launch_bounds__(512) void k_scan2(int* __restrict__ bsum) {
  __shared__ int tmp[512];
  int t = threadIdx.x;
  int v = (t < NB) ? bsum[t] : 0;
  tmp[t] = v;
  __syncthreads();
  for (int o = 1; o < 512; o <<= 1) {
    int u = (t >= o) ? tmp[t - o] : 0;
    __syncthreads();
    tmp[t] += u;
    __syncthreads();
  }
  bsum[t] = tmp[t] - v;
}

// also finalizes dv = rsqrt(deg+1)
__global__ __launch_bounds__(256) void k_scan3(int* __restrict__ off,
                                               const int* __restrict__ bsum,
                                               int* __restrict__ cur,
                                               float* __restrict__ dv) {
  int i = blockIdx.x * 256 + threadIdx.x;
  if (i < NN) {
    int o = off[i] + bsum[i >> 8];
    off[i] = o;
    cur[i] = o;
    dv[i] = rsqrtf(dv[i] + 1.0f);
  }
}

__global__ __launch_bounds__(256) void k_place(const int* __restrict__ ei,
                                               const float* __restrict__ ew,
                                               const float* __restrict__ dv,
                                               int* __restrict__ cur,
                                               int2* __restrict__ elist) {
  int e = blockIdx.x * 256 + threadIdx.x;
  if (e >= NE) return;
  int s = ei[e];
  int d = ei[NE + e];
  float c = dv[s] * ew[e] * dv[d];
  int pos = atomicAdd(&cur[d], 1);
  elist[pos] = make_int2(s, __float_as_int(c));
}

// Pre-pack W (f32 [k][c]) into fragment-major bf16 Wf:
// short index = ((k>>5)*16 + (c>>4))*512 + ((c&15) + ((k>>3)&3)*16)*8 + (k&7)
__global__ __launch_bounds__(256) void k_wprep(const float* __restrict__ W,
                                               short* __restrict__ Wf) {
  int idx = blockIdx.x * 256 + threadIdx.x;  // 16384 total
  int k = idx >> 6;
  int c4 = idx & 63;
  const float4 v = *(const float4*)(W + k * 256 + c4 * 4);
  float vv[4] = {v.x, v.y, v.z, v.w};
#pragma unroll
  for (int i = 0; i < 4; ++i) {
    int c = c4 * 4 + i;
    int di = ((k >> 5) * 16 + (c >> 4)) * 512 + ((c & 15) + ((k >> 3) & 3) * 16) * 8 + (k & 7);
    Wf[di] = f2bf(vv[i]);
  }
}

// h = bf16(x @ W). BM=64, BN=256, K=256. 8 waves (2 row x 4 col strips).
// R6 structure verbatim (best measured, 66us): register staging with
// 4-region LDS fill, raw s_barrier with lgkmcnt(0) only (no vmcnt drain in
// the loop; the compiler's own rolling vmcnt pipelines the 8 loads).
__global__ __launch_bounds__(512, 2) void k_gemm(const float* __restrict__ x,
                                                 const short* __restrict__ Wf,
                                                 short* __restrict__ h) {
  __shared__ short As[64 * 256];  // 32 KB, rows 512B, XOR-swizzled

  const int t = threadIdx.x;
  const int lane = t & 63;
  const int wid = t >> 6;
  const int row0 = blockIdx.x * 64;
  const int wrow = (wid >> 2) * 32;   // node-row offset: 0 or 32
  const int wstrip = wid & 3;         // 64-col strip

  // ---- issue ALL staging loads (one row, one 8-elem chunk col, 4 K-regions)
  const int rr = t >> 3;   // row 0..63
  const int kc = t & 7;    // 8-elem chunk within a 64-k region
  int grow = row0 + rr;
  if (grow > NN - 1) grow = NN - 1;   // clamp; OOB rows discarded at store
  const float* rp = x + (size_t)grow * 256 + kc * 8;
  float4 a0 = *(const float4*)(rp);        float4 b0 = *(const float4*)(rp + 4);
  float4 a1 = *(const float4*)(rp + 64);   float4 b1 = *(const float4*)(rp + 68);
  float4 a2 = *(const float4*)(rp + 128);  float4 b2 = *(const float4*)(rp + 132);
  float4 a3 = *(const float4*)(rp + 192);  float4 b3 = *(const float4*)(rp + 196);

  // swizzled write byte for region 0; region i adds i*128 (XOR bits < 128)
  const int wb = (rr * 512 + kc * 16) ^ ((rr & 7) << 4);

#define WRITE_REGION(I, A, B)                                              \
  {                                                                        \
    short8 s_;                                                             \
    s_[0] = f2bf(A.x); s_[1] = f2bf(A.y); s_[2] = f2bf(A.z);               \
    s_[3] = f2bf(A.w); s_[4] = f2bf(B.x); s_[5] = f2bf(B.y);               \
    s_[6] = f2bf(B.z); s_[7] = f2bf(B.w);                                  \
    *(short8*)((char*)As + wb + (I)*128) = s_;                             \
  }

#define BARSYNC                                                            \
  asm volatile("s_waitcnt lgkmcnt(0)" ::: "memory");                       \
  __builtin_amdgcn_s_barrier();

  f32x4 acc[4][2];
#pragma unroll
  for (int mc = 0; mc < 4; ++mc)
#pragma unroll
    for (int nr = 0; nr < 2; ++nr) acc[mc][nr] = (f32x4)0.0f;

  const short* wbase = Wf + (size_t)(wstrip * 4) * 512 + lane * 8;

#define COMPUTE_REGION(I)                                                  \
  _Pragma("unroll")                                                        \
  for (int ks2 = 0; ks2 < 2; ++ks2) {                                      \
    const int ks = 2 * (I) + ks2;                                          \
    short8 bx[2];                                                          \
    short8 aw[4];                                                          \
    _Pragma("unroll")                                                      \
    for (int nr = 0; nr < 2; ++nr) {                                       \
      int r_ = wrow + nr * 16 + (lane & 15);                               \
      int byte_ = (r_ * 512 + ks * 64 + (lane >> 4) * 16) ^ ((r_ & 7) << 4); \
      bx[nr] = *(short8*)((char*)As + byte_);                              \
    }                                                                      \
    _Pragma("unroll")                                                      \
    for (int mc = 0; mc < 4; ++mc)                                         \
      aw[mc] = *(const short8*)(wbase + (size_t)(ks * 16 + mc) * 512);     \
    _Pragma("unroll")                                                      \
    for (int mc = 0; mc < 4; ++mc)                                         \
      _Pragma("unroll")                                                    \
      for (int nr = 0; nr < 2; ++nr)                                       \
        acc[mc][nr] = __builtin_amdgcn_mfma_f32_16x16x32_bf16(             \
            aw[mc], bx[nr], acc[mc][nr], 0, 0, 0);                         \
  }

  WRITE_REGION(0, a0, b0);
  BARSYNC;
  COMPUTE_REGION(0);
  WRITE_REGION(1, a1, b1);
  BARSYNC;
  COMPUTE_REGION(1);
  WRITE_REGION(2, a2, b2);
  BARSYNC;
  COMPUTE_REGION(2);
  WRITE_REGION(3, a3, b3);
  BARSYNC;
  COMPUTE_REGION(3);

#undef WRITE_REGION
#undef BARSYNC
#undef COMPUTE_REGION

  // ---- epilogue: D[row=W-col][col=node-row]; lane packs 4 consecutive cols.
#pragma unroll
  for (int mc = 0; mc < 4; ++mc) {
    int cbase = wstrip * 64 + mc * 16 + 4 * (lane >> 4);
#pragma unroll
    for (int nr = 0; nr < 2; ++nr) {
      int r = row0 + wrow + nr * 16 + (lane & 15);
      if (r < NN) {
        union { u16x4 s; unsigned u[2]; } S;
        S.u[0] = cvtpk(acc[mc][nr][0], acc[mc][nr][1]);
        S.u[1] = cvtpk(acc[mc][nr][2], acc[mc][nr][3]);
        *(u16x4*)(h + (size_t)r * 256 + cbase) = S.s;
      }
    }
  }
}

// gather-aggregate + self-loop + bias + LayerNorm + residual + relu.
// One node per 32-lane half-wave; edge loop unrolled by 4 + serial remainder.
__global__ __launch_bounds__(256) void k_agg(const short* __restrict__ h,
                                             const float* __restrict__ dv,
                                             const int* __restrict__ cnt,
                                             const int* __restrict__ off,
                                             const int2* __restrict__ elist,
                                             const float* __restrict__ x,
                                             const float* __restrict__ b,
                                             const float* __restrict__ gamma,
                                             const float* __restrict__ beta,
                                             float* __restrict__ out) {
  int node = (blockIdx.x * 256 + threadIdx.x) >> 5;
  if (node >= NN) return;
  int q = threadIdx.x & 31;           // sublane: features q*8 .. q*8+7

  const float di = dv[node];
  const float d2 = di * di;
  short8 hv = *(const short8*)(h + (size_t)node * 256 + q * 8);
  float a[8];
#pragma unroll
  for (int i = 0; i < 8; ++i) a[i] = bf2f(hv[i]) * d2;

  const int n = cnt[node];
  const int st = off[node];
  int j = 0;
  for (; j + 4 <= n; j += 4) {
    int2 r0 = elist[st + j];
    int2 r1 = elist[st + j + 1];
    int2 r2 = elist[st + j + 2];
    int2 r3 = elist[st + j + 3];
    short8 g0 = *(const short8*)(h + (size_t)r0.x * 256 + q * 8);
    short8 g1 = *(const short8*)(h + (size_t)r1.x * 256 + q * 8);
    short8 g2 = *(const short8*)(h + (size_t)r2.x * 256 + q * 8);
    short8 g3 = *(const short8*)(h + (size_t)r3.x * 256 + q * 8);
    float c0 = __int_as_float(r0.y);
    float c1 = __int_as_float(r1.y);
    float c2 = __int_as_float(r2.y);
    float c3 = __int_as_float(r3.y);
#pragma unroll
    for (int i = 0; i < 8; ++i)
      a[i] += c0 * bf2f(g0[i]) + c1 * bf2f(g1[i]) + c2 * bf2f(g2[i]) + c3 * bf2f(g3[i]);
  }
  for (; j < n; ++j) {
    int2 r0 = elist[st + j];
    short8 g0 = *(const short8*)(h + (size_t)r0.x * 256 + q * 8);
    float c0 = __int_as_float(r0.y);
#pragma unroll
    for (int i = 0; i < 8; ++i) a[i] += c0 * bf2f(g0[i]);
  }

  const float4 b0 = *(const float4*)(b + q * 8);
  const float4 b1 = *(const float4*)(b + q * 8 + 4);
  a[0] += b0.x; a[1] += b0.y; a[2] += b0.z; a[3] += b0.w;
  a[4] += b1.x; a[5] += b1.y; a[6] += b1.z; a[7] += b1.w;

  float s = 0.f, ss = 0.f;
#pragma unroll
  for (int i = 0; i < 8; ++i) { s += a[i]; ss += a[i] * a[i]; }
#pragma unroll
  for (int o = 16; o > 0; o >>= 1) {
    s += __shfl_xor(s, o);
    ss += __shfl_xor(ss, o);
  }
  const float mu = s * (1.0f / 256.0f);
  const float var = ss * (1.0f / 256.0f) - mu * mu;
  const float inv = rsqrtf(var + 1e-5f);

  const float4 g0 = *(const float4*)(gamma + q * 8);
  const float4 g1 = *(const float4*)(gamma + q * 8 + 4);
  const float4 e0 = *(const float4*)(beta + q * 8);
  const float4 e1 = *(const float4*)(beta + q * 8 + 4);
  const float4 x0 = *(const float4*)(x + (size_t)node * 256 + q * 8);
  const float4 x1 = *(const float4*)(x + (size_t)node * 256 + q * 8 + 4);

  float4 r0, r1;
  r0.x = fmaxf(0.5f * ((a[0] - mu) * inv * g0.x + e0.x) + 0.5f * x0.x, 0.f);
  r0.y = fmaxf(0.5f * ((a[1] - mu) * inv * g0.y + e0.y) + 0.5f * x0.y, 0.f);
  r0.z = fmaxf(0.5f * ((a[2] - mu) * inv * g0.z + e0.z) + 0.5f * x0.z, 0.f);
  r0.w = fmaxf(0.5f * ((a[3] - mu) * inv * g0.w + e0.w) + 0.5f * x0.w, 0.f);
  r1.x = fmaxf(0.5f * ((a[4] - mu) * inv * g1.x + e1.x) + 0.5f * x1.x, 0.f);
  r1.y = fmaxf(0.5f * ((a[5] - mu) * inv * g1.y + e1.y) + 0.5f * x1.y, 0.f);
  r1.z = fmaxf(0.5f * ((a[6] - mu) * inv * g1.z + e1.z) + 0.5f * x1.z, 0.f);
  r1.w = fmaxf(0.5f * ((a[7] - mu) * inv * g1.w + e1.w) + 0.5f * x1.w, 0.f);

  float* o = out + (size_t)node * 256 + q * 8;
  *(float4*)(o) = r0;
  *(float4*)(o + 4) = r1;
}

extern "C" void kernel_launch(void* const* d_in, const int* in_sizes, int n_in,
                              void* d_out, int out_size, void* d_ws, size_t ws_size,
                              hipStream_t stream) {
  const float* x     = (const float*)d_in[0];
  const int*   ei    = (const int*)d_in[1];
  const float* ew    = (const float*)d_in[2];
  const float* W     = (const float*)d_in[3];
  const float* b     = (const float*)d_in[4];
  const float* gamma = (const float*)d_in[5];
  const float* beta  = (const float*)d_in[6];
  float* out = (float*)d_out;

  short* h   = (short*)d_ws;                       // N*256 bf16
  float* dv  = (float*)(h + (size_t)NN * DD);      // N floats
  int*   cnt = (int*)(dv + NN);                    // N ints
  int*   off = cnt + NN;                           // N ints
  int*   cur = off + NN;                           // N ints
  int*   bsum = cur + NN;                          // 512 ints
  int2*  elist = (int2*)(bsum + 512);              // NE int2
  short* Wf  = (short*)(elist + NE);               // 65536 shorts

  (void)hipMemsetAsync(dv, 0, NN * sizeof(float), stream);
  (void)hipMemsetAsync(cnt, 0, NN * sizeof(int), stream);

  k_wprep<<<64, 256, 0, stream>>>(W, Wf);
  k_gemm<<<GMB, 512, 0, stream>>>(x, Wf, h);

  k_hist<<<(NE + 255) / 256, 256, 0, stream>>>(ei, ew, dv, cnt);
  k_scan1<<<NB, 256, 0, stream>>>(cnt, off, bsum);
  k_scan2<<<1, 512, 0, stream>>>(bsum);
  k_scan3<<<NB, 256, 0, stream>>>(off, bsum, cur, dv);
  k_place<<<(NE + 255) / 256, 256, 0, stream>>>(ei, ew, dv, cur, elist);

  k_agg<<<(NN * 32 + 255) / 256, 256, 0, stream>>>(h, dv, cnt, off, elist, x, b, gamma, beta, out);
}